// Round 10
// baseline (206.883 us; speedup 1.0000x reference)
//
#include <hip/hip_runtime.h>
#include <hip/hip_bf16.h>
#include <cstdint>
#include <cstddef>

#define BB 128
#define SS 4096
#define HH 128
#define N1 256
#define N2 64
#define BROWS 256   // rows per block = 8 waves * 32 rows; 256 | 4096 -> one b per block

typedef __bf16 bf16x8 __attribute__((ext_vector_type(8)));
typedef __bf16 bf16x4 __attribute__((ext_vector_type(4)));
typedef float  f32x4  __attribute__((ext_vector_type(4)));

// ---------------------------------------------------------------------------
// Merged prologue (layouts verified rounds 4-9).
// Blocks 0..23: weight frags. Blocks 24..151: an partial.
// w1f (nodes half, 64 KB): frag(g 0..15, ks 0..3):
//   val[l][j] = W1[32ks + 8*(l>>4) + j][16g + (l&15)]
// w2f (32 KB): A-frags of W2^T, n-split k-slot relabel:
//   frag(mt2 0..3, ksp 0..7): val[l][j] = W2[c][16mt2 + (l&15)],
//   c = 32ksp + 16*(j>>2) + 4*(l>>4) + (j&3)
// an[b][c] = b1[c] + newn[b,:] . W1[128:256, c]
// ---------------------------------------------------------------------------
__global__ __launch_bounds__(256) void prologue(
    const float* __restrict__ W1, const float* __restrict__ W2,
    const float* __restrict__ b1, const float* __restrict__ newn,
    __bf16* __restrict__ w1f, __bf16* __restrict__ w2f, __bf16* __restrict__ an)
{
    const int blk = blockIdx.x;
    if (blk < 24) {
        int tid = blk * 256 + threadIdx.x;
        if (tid < 4096) {                        // W1 nodes half: 16 g * 4 ks * 64 lanes
            int lane = tid & 63, ks = (tid >> 6) & 3, g = tid >> 8;
            int col = 16 * g + (lane & 15);
            int kbase = 32 * ks + 8 * (lane >> 4);
            bf16x8 v;
#pragma unroll
            for (int j = 0; j < 8; ++j) v[j] = (__bf16)W1[(size_t)(kbase + j) * N1 + col];
            *(bf16x8*)(w1f + (size_t)tid * 8) = v;
        } else {                                 // W2: 4 mt2 * 8 ksp * 64 lanes
            int s = tid - 4096;
            int lane = s & 63, ksp = (s >> 6) & 7, mt2 = s >> 9;
            int q = lane >> 4, ln = lane & 15;
            bf16x8 v;
#pragma unroll
            for (int j = 0; j < 8; ++j) {
                int c = 32 * ksp + 16 * (j >> 2) + 4 * q + (j & 3);
                v[j] = (__bf16)W2[(size_t)c * N2 + 16 * mt2 + ln];
            }
            *(bf16x8*)(w2f + (size_t)s * 8) = v;
        }
    } else {
        const int b = blk - 24, c = threadIdx.x;
        float acc = b1[c];
        const float* wp = W1 + (size_t)HH * N1 + c;   // rows 128..255, col c
        const float* nv = newn + (size_t)b * HH;
#pragma unroll 8
        for (int k = 0; k < HH; ++k)
            acc = fmaf(nv[k], wp[(size_t)k * N1], acc);
        an[(size_t)b * N1 + c] = (__bf16)acc;
    }
}

// ---------------------------------------------------------------------------
// Main kernel = round-8 structure (best measured: 83.7 us) + two stall fixes.
// 512 threads = 8 waves; wave w owns rows 32w..32w+31 (2 rowsets of 16).
// X loads issue FIRST, then the w1 LDS staging, then the single barrier:
// the barrier's vmcnt(0) drain covers BOTH bursts in one HBM round-trip
// (round 9 proved reordering these costs ~25 us).
// w1 (64 KB) in LDS -> 2 blocks/CU resident, 4 waves/SIMD (VGPR<=128).
// w2 frags (32 KB, L1/L2-hot broadcast) stream via VMEM per ksp.
// Round-10 additions:
//  (1) #pragma unroll 2 on the ksp loop: compiler software-pipelines the
//      next iteration's af (LDS, ~120cy) and a2f (VMEM, ~200cy) loads under
//      the current iteration's MFMAs -- unroll 1 blocked that.
//  (2) s_setprio(1) around the MFMA-dense region (T5): waves here de-phase
//      (no per-ksp barrier), so load-phase vs MFMA-phase wave diversity
//      exists for the CU scheduler to arbitrate.
// ---------------------------------------------------------------------------
__global__ __launch_bounds__(512, 4) void edge_mlp_mfma9(
    const float* __restrict__ nodes,
    const float* __restrict__ b2,
    const float* __restrict__ W3, const float* __restrict__ b3,
    const __bf16* __restrict__ w1f,    // 32768 elems in ws
    const __bf16* __restrict__ w2f,    // 16384 elems in ws
    const __bf16* __restrict__ an,
    float* __restrict__ out)
{
    __shared__ __bf16 w1s[32768];      // 64 KB

    const int t = threadIdx.x;
    const int w = t >> 6, l = t & 63, q = l >> 4, ln = l & 15;
    const size_t row0 = (size_t)blockIdx.x * BROWS;
    const int b = (int)(row0 >> 12);

    // ---- X frags (global->reg, issued BEFORE staging/barrier): [rs][ks] ----
    bf16x8 xf[2][4];
#pragma unroll
    for (int rs = 0; rs < 2; ++rs) {
        const float* rp = nodes + (row0 + 32 * w + 16 * rs + ln) * HH + 8 * q;
#pragma unroll
        for (int ks = 0; ks < 4; ++ks) {
            float4 f0 = *(const float4*)(rp + 32 * ks);
            float4 f1 = *(const float4*)(rp + 32 * ks + 4);
            bf16x8 v;
            v[0] = (__bf16)f0.x; v[1] = (__bf16)f0.y; v[2] = (__bf16)f0.z; v[3] = (__bf16)f0.w;
            v[4] = (__bf16)f1.x; v[5] = (__bf16)f1.y; v[6] = (__bf16)f1.z; v[7] = (__bf16)f1.w;
            xf[rs][ks] = v;
        }
    }

    // ---- stage w1 frags: 4096 uint4 = 64 KB, coalesced flat copy ----
#pragma unroll
    for (int i = 0; i < 8; ++i) {
        int idx = i * 512 + t;
        ((uint4*)w1s)[idx] = ((const uint4*)w1f)[idx];
    }

    // ---- h2 accumulators [rs][mt2], bias-initialized ----
    f32x4 acc2[2][4];
#pragma unroll
    for (int mt2 = 0; mt2 < 4; ++mt2) {
        float4 bv = *(const float4*)(b2 + 16 * mt2 + 4 * q);
#pragma unroll
        for (int rs = 0; rs < 2; ++rs) {
            acc2[rs][mt2][0] = bv.x; acc2[rs][mt2][1] = bv.y;
            acc2[rs][mt2][2] = bv.z; acc2[rs][mt2][3] = bv.w;
        }
    }

    const __bf16* anb = an + (size_t)b * N1;

    __syncthreads();   // one drain covers staging + X loads together

    // ---- main loop over g-pairs / layer-2 k-steps ----
#pragma unroll 2
    for (int ksp = 0; ksp < 8; ++ksp) {
        bf16x8 af0[4], af1[4], a2f[4];
#pragma unroll
        for (int mt2 = 0; mt2 < 4; ++mt2)
            a2f[mt2] = *(const bf16x8*)(w2f + ((size_t)(mt2 * 8 + ksp) * 64 + l) * 8);
#pragma unroll
        for (int ks = 0; ks < 4; ++ks) {
            af0[ks] = *(const bf16x8*)(w1s + ((size_t)((2 * ksp)     * 4 + ks) * 64 + l) * 8);
            af1[ks] = *(const bf16x8*)(w1s + ((size_t)((2 * ksp + 1) * 4 + ks) * 64 + l) * 8);
        }

        // newn+bias partial for this g-pair (broadcast 8B loads, L1-hot)
        f32x4 an0, an1;
        {
            bf16x4 a0 = *(const bf16x4*)(anb + 32 * ksp + 4 * q);
            bf16x4 a1 = *(const bf16x4*)(anb + 32 * ksp + 16 + 4 * q);
#pragma unroll
            for (int j = 0; j < 4; ++j) { an0[j] = (float)a0[j]; an1[j] = (float)a1[j]; }
        }

        __builtin_amdgcn_s_setprio(1);
#pragma unroll
        for (int rs = 0; rs < 2; ++rs) {
            f32x4 alo = an0, ahi = an1;
#pragma unroll
            for (int ks = 0; ks < 4; ++ks) {
                alo = __builtin_amdgcn_mfma_f32_16x16x32_bf16(af0[ks], xf[rs][ks], alo, 0, 0, 0);
                ahi = __builtin_amdgcn_mfma_f32_16x16x32_bf16(af1[ks], xf[rs][ks], ahi, 0, 0, 0);
            }
            bf16x8 bfrag;
#pragma unroll
            for (int j = 0; j < 4; ++j) {
                bfrag[j]     = (__bf16)fmaxf(alo[j], 0.0f);
                bfrag[4 + j] = (__bf16)fmaxf(ahi[j], 0.0f);
            }
#pragma unroll
            for (int mt2 = 0; mt2 < 4; ++mt2)
                acc2[rs][mt2] = __builtin_amdgcn_mfma_f32_16x16x32_bf16(a2f[mt2], bfrag, acc2[rs][mt2], 0, 0, 0);
        }
        __builtin_amdgcn_s_setprio(0);
    }

    // ---- layer 3: relu(h2).W3 + b3, reduce over q-groups, sigmoid ----
    const float b3v = b3[0];
#pragma unroll
    for (int rs = 0; rs < 2; ++rs) {
        float sum = 0.f;
#pragma unroll
        for (int mt2 = 0; mt2 < 4; ++mt2) {
            float4 w3v = *(const float4*)(W3 + 16 * mt2 + 4 * q);
            sum += fmaxf(acc2[rs][mt2][0], 0.f) * w3v.x
                 + fmaxf(acc2[rs][mt2][1], 0.f) * w3v.y
                 + fmaxf(acc2[rs][mt2][2], 0.f) * w3v.z
                 + fmaxf(acc2[rs][mt2][3], 0.f) * w3v.w;
        }
        sum += __shfl_xor(sum, 16, 64);
        sum += __shfl_xor(sum, 32, 64);
        if (q == 0) {
            float v = sum + b3v;
            out[row0 + 32 * w + 16 * rs + ln] = 1.0f / (1.0f + __expf(-v));
        }
    }
}

// ---------------------------------------------------------------------------
// fp32 fallback if workspace is too small
// ---------------------------------------------------------------------------
__global__ __launch_bounds__(256, 4) void edge_mlp_f32(
    const float* __restrict__ nodes, const float* __restrict__ newn,
    const float* __restrict__ W1, const float* __restrict__ b1,
    const float* __restrict__ W2, const float* __restrict__ b2,
    const float* __restrict__ W3, const float* __restrict__ b3,
    float* __restrict__ out)
{
    __shared__ float buf[32][256];
    const int t = threadIdx.x;
    const long r0 = (long)blockIdx.x * 32;
    const int b = (int)(r0 >> 12);
    const float4* src = (const float4*)(nodes + (size_t)r0 * HH);
#pragma unroll
    for (int i = 0; i < 4; ++i) {
        int idx = t + i * 256;
        *(float4*)&buf[idx >> 5][(idx & 31) * 4] = src[idx];
    }
    {
        float nv = newn[b * HH + (t & 127)];
        for (int r = (t >> 7); r < 32; r += 2) buf[r][HH + (t & 127)] = nv;
    }
    __syncthreads();
    const int c0 = t & 63, rb = (t >> 6) * 8;
    float acc[8][4];
#pragma unroll
    for (int ci = 0; ci < 4; ++ci) {
        float bv = b1[c0 + 64 * ci];
#pragma unroll
        for (int r = 0; r < 8; ++r) acc[r][ci] = bv;
    }
    for (int k = 0; k < 256; k += 4) {
        float wv[4][4];
#pragma unroll
        for (int kk = 0; kk < 4; ++kk)
#pragma unroll
            for (int ci = 0; ci < 4; ++ci) wv[kk][ci] = W1[(k + kk) * N1 + c0 + 64 * ci];
#pragma unroll
        for (int r = 0; r < 8; ++r) {
            float4 x = *(const float4*)&buf[rb + r][k];
#pragma unroll
            for (int ci = 0; ci < 4; ++ci) {
                acc[r][ci] = fmaf(x.x, wv[0][ci], acc[r][ci]);
                acc[r][ci] = fmaf(x.y, wv[1][ci], acc[r][ci]);
                acc[r][ci] = fmaf(x.z, wv[2][ci], acc[r][ci]);
                acc[r][ci] = fmaf(x.w, wv[3][ci], acc[r][ci]);
            }
        }
    }
    __syncthreads();
#pragma unroll
    for (int r = 0; r < 8; ++r)
#pragma unroll
        for (int ci = 0; ci < 4; ++ci) buf[rb + r][c0 + 64 * ci] = fmaxf(acc[r][ci], 0.0f);
    __syncthreads();
    const int c2 = t & 31, g2 = t >> 5;
    float acc2[4][2];
#pragma unroll
    for (int cj = 0; cj < 2; ++cj) {
        float bv = b2[c2 + 32 * cj];
#pragma unroll
        for (int rr = 0; rr < 4; ++rr) acc2[rr][cj] = bv;
    }
    for (int k = 0; k < 256; k += 4) {
        float w2v[4][2];
#pragma unroll
        for (int kk = 0; kk < 4; ++kk)
#pragma unroll
            for (int cj = 0; cj < 2; ++cj) w2v[kk][cj] = W2[(k + kk) * N2 + c2 + 32 * cj];
#pragma unroll
        for (int rr = 0; rr < 4; ++rr) {
            float4 x = *(const float4*)&buf[4 * g2 + rr][k];
#pragma unroll
            for (int cj = 0; cj < 2; ++cj) {
                acc2[rr][cj] = fmaf(x.x, w2v[0][cj], acc2[rr][cj]);
                acc2[rr][cj] = fmaf(x.y, w2v[1][cj], acc2[rr][cj]);
                acc2[rr][cj] = fmaf(x.z, w2v[2][cj], acc2[rr][cj]);
                acc2[rr][cj] = fmaf(x.w, w2v[3][cj], acc2[rr][cj]);
            }
        }
    }
    const float w3a = W3[c2], w3b = W3[c2 + 32], b3v = b3[0];
    float p[4];
#pragma unroll
    for (int rr = 0; rr < 4; ++rr)
        p[rr] = fmaf(fmaxf(acc2[rr][0], 0.f), w3a, fmaxf(acc2[rr][1], 0.f) * w3b);
#pragma unroll
    for (int off = 16; off >= 1; off >>= 1)
#pragma unroll
        for (int rr = 0; rr < 4; ++rr) p[rr] += __shfl_xor(p[rr], off, 64);
    if (c2 == 0)
#pragma unroll
        for (int rr = 0; rr < 4; ++rr)
            out[r0 + 4 * g2 + rr] = 1.0f / (1.0f + __expf(-(p[rr] + b3v)));
}

extern "C" void kernel_launch(void* const* d_in, const int* in_sizes, int n_in,
                              void* d_out, int out_size, void* d_ws, size_t ws_size,
                              hipStream_t stream) {
    const float* nodes = (const float*)d_in[0];
    const float* newn  = (const float*)d_in[1];
    const float* W1    = (const float*)d_in[2];
    const float* b1    = (const float*)d_in[3];
    const float* W2    = (const float*)d_in[4];
    const float* b2    = (const float*)d_in[5];
    const float* W3    = (const float*)d_in[6];
    const float* b3    = (const float*)d_in[7];
    float* out = (float*)d_out;
    const int M = BB * SS;

    if (ws_size >= 163840) {               // 64K w1f + 32K w2f + 64K an
        __bf16* w1f = (__bf16*)d_ws;                   // 32768 elems
        __bf16* w2f = (__bf16*)d_ws + 32768;           // 16384 elems
        __bf16* anp = (__bf16*)d_ws + 49152;           // 32768 elems
        hipLaunchKernelGGL(prologue, dim3(24 + BB), dim3(256), 0, stream,
                           W1, W2, b1, newn, w1f, w2f, anp);
        hipLaunchKernelGGL(edge_mlp_mfma9, dim3(M / BROWS), dim3(512), 0, stream,
                           nodes, b2, W3, b3, w1f, w2f, anp, out);
    } else {
        hipLaunchKernelGGL(edge_mlp_f32, dim3(M / 32), dim3(256), 0, stream,
                           nodes, newn, W1, b1, W2, b2, W3, b3, out);
    }
}

// Round 11
// 206.153 us; speedup vs baseline: 1.0035x; 1.0035x over previous
//
#include <hip/hip_runtime.h>
#include <hip/hip_bf16.h>
#include <cstdint>
#include <cstddef>

#define BB 128
#define SS 4096
#define HH 128
#define N1 256
#define N2 64
#define BROWS 256   // rows per block = 8 waves * 32 rows; 256 | 4096 -> one b per block

typedef __bf16 bf16x8 __attribute__((ext_vector_type(8)));
typedef __bf16 bf16x4 __attribute__((ext_vector_type(4)));
typedef float  f32x4  __attribute__((ext_vector_type(4)));

// ---------------------------------------------------------------------------
// Merged prologue (layouts verified rounds 4-9).
// Blocks 0..23: weight frags. Blocks 24..151: an partial.
// w1f (nodes half, 64 KB): frag(g 0..15, ks 0..3):
//   val[l][j] = W1[32ks + 8*(l>>4) + j][16g + (l&15)]
// w2f (32 KB): A-frags of W2^T, n-split k-slot relabel:
//   frag(mt2 0..3, ksp 0..7): val[l][j] = W2[c][16mt2 + (l&15)],
//   c = 32ksp + 16*(j>>2) + 4*(l>>4) + (j&3)
// an[b][c] = b1[c] + newn[b,:] . W1[128:256, c]
// ---------------------------------------------------------------------------
__global__ __launch_bounds__(256) void prologue(
    const float* __restrict__ W1, const float* __restrict__ W2,
    const float* __restrict__ b1, const float* __restrict__ newn,
    __bf16* __restrict__ w1f, __bf16* __restrict__ w2f, __bf16* __restrict__ an)
{
    const int blk = blockIdx.x;
    if (blk < 24) {
        int tid = blk * 256 + threadIdx.x;
        if (tid < 4096) {                        // W1 nodes half: 16 g * 4 ks * 64 lanes
            int lane = tid & 63, ks = (tid >> 6) & 3, g = tid >> 8;
            int col = 16 * g + (lane & 15);
            int kbase = 32 * ks + 8 * (lane >> 4);
            bf16x8 v;
#pragma unroll
            for (int j = 0; j < 8; ++j) v[j] = (__bf16)W1[(size_t)(kbase + j) * N1 + col];
            *(bf16x8*)(w1f + (size_t)tid * 8) = v;
        } else {                                 // W2: 4 mt2 * 8 ksp * 64 lanes
            int s = tid - 4096;
            int lane = s & 63, ksp = (s >> 6) & 7, mt2 = s >> 9;
            int q = lane >> 4, ln = lane & 15;
            bf16x8 v;
#pragma unroll
            for (int j = 0; j < 8; ++j) {
                int c = 32 * ksp + 16 * (j >> 2) + 4 * q + (j & 3);
                v[j] = (__bf16)W2[(size_t)c * N2 + 16 * mt2 + ln];
            }
            *(bf16x8*)(w2f + (size_t)s * 8) = v;
        }
    } else {
        const int b = blk - 24, c = threadIdx.x;
        float acc = b1[c];
        const float* wp = W1 + (size_t)HH * N1 + c;   // rows 128..255, col c
        const float* nv = newn + (size_t)b * HH;
#pragma unroll 8
        for (int k = 0; k < HH; ++k)
            acc = fmaf(nv[k], wp[(size_t)k * N1], acc);
        an[(size_t)b * N1 + c] = (__bf16)acc;
    }
}

// ---------------------------------------------------------------------------
// Main kernel = round-8 structure (best measured: 83.7 us) + two stall fixes.
// 512 threads = 8 waves; wave w owns rows 32w..32w+31 (2 rowsets of 16).
// X loads issue FIRST, then the w1 LDS staging, then the single barrier:
// the barrier's vmcnt(0) drain covers BOTH bursts in one HBM round-trip
// (round 9 proved reordering these costs ~25 us).
// w1 (64 KB) in LDS -> 2 blocks/CU resident, 4 waves/SIMD (VGPR<=128).
// w2 frags (32 KB, L1/L2-hot broadcast) stream via VMEM per ksp.
// Round-10 additions:
//  (1) #pragma unroll 2 on the ksp loop: compiler software-pipelines the
//      next iteration's af (LDS, ~120cy) and a2f (VMEM, ~200cy) loads under
//      the current iteration's MFMAs -- unroll 1 blocked that.
//  (2) s_setprio(1) around the MFMA-dense region (T5): waves here de-phase
//      (no per-ksp barrier), so load-phase vs MFMA-phase wave diversity
//      exists for the CU scheduler to arbitrate.
// ---------------------------------------------------------------------------
__global__ __launch_bounds__(512, 4) void edge_mlp_mfma9(
    const float* __restrict__ nodes,
    const float* __restrict__ b2,
    const float* __restrict__ W3, const float* __restrict__ b3,
    const __bf16* __restrict__ w1f,    // 32768 elems in ws
    const __bf16* __restrict__ w2f,    // 16384 elems in ws
    const __bf16* __restrict__ an,
    float* __restrict__ out)
{
    __shared__ __bf16 w1s[32768];      // 64 KB

    const int t = threadIdx.x;
    const int w = t >> 6, l = t & 63, q = l >> 4, ln = l & 15;
    const size_t row0 = (size_t)blockIdx.x * BROWS;
    const int b = (int)(row0 >> 12);

    // ---- X frags (global->reg, issued BEFORE staging/barrier): [rs][ks] ----
    bf16x8 xf[2][4];
#pragma unroll
    for (int rs = 0; rs < 2; ++rs) {
        const float* rp = nodes + (row0 + 32 * w + 16 * rs + ln) * HH + 8 * q;
#pragma unroll
        for (int ks = 0; ks < 4; ++ks) {
            float4 f0 = *(const float4*)(rp + 32 * ks);
            float4 f1 = *(const float4*)(rp + 32 * ks + 4);
            bf16x8 v;
            v[0] = (__bf16)f0.x; v[1] = (__bf16)f0.y; v[2] = (__bf16)f0.z; v[3] = (__bf16)f0.w;
            v[4] = (__bf16)f1.x; v[5] = (__bf16)f1.y; v[6] = (__bf16)f1.z; v[7] = (__bf16)f1.w;
            xf[rs][ks] = v;
        }
    }

    // ---- stage w1 frags: 4096 uint4 = 64 KB, coalesced flat copy ----
#pragma unroll
    for (int i = 0; i < 8; ++i) {
        int idx = i * 512 + t;
        ((uint4*)w1s)[idx] = ((const uint4*)w1f)[idx];
    }

    // ---- h2 accumulators [rs][mt2], bias-initialized ----
    f32x4 acc2[2][4];
#pragma unroll
    for (int mt2 = 0; mt2 < 4; ++mt2) {
        float4 bv = *(const float4*)(b2 + 16 * mt2 + 4 * q);
#pragma unroll
        for (int rs = 0; rs < 2; ++rs) {
            acc2[rs][mt2][0] = bv.x; acc2[rs][mt2][1] = bv.y;
            acc2[rs][mt2][2] = bv.z; acc2[rs][mt2][3] = bv.w;
        }
    }

    const __bf16* anb = an + (size_t)b * N1;

    __syncthreads();   // one drain covers staging + X loads together

    // ---- main loop over g-pairs / layer-2 k-steps ----
#pragma unroll 2
    for (int ksp = 0; ksp < 8; ++ksp) {
        bf16x8 af0[4], af1[4], a2f[4];
#pragma unroll
        for (int mt2 = 0; mt2 < 4; ++mt2)
            a2f[mt2] = *(const bf16x8*)(w2f + ((size_t)(mt2 * 8 + ksp) * 64 + l) * 8);
#pragma unroll
        for (int ks = 0; ks < 4; ++ks) {
            af0[ks] = *(const bf16x8*)(w1s + ((size_t)((2 * ksp)     * 4 + ks) * 64 + l) * 8);
            af1[ks] = *(const bf16x8*)(w1s + ((size_t)((2 * ksp + 1) * 4 + ks) * 64 + l) * 8);
        }

        // newn+bias partial for this g-pair (broadcast 8B loads, L1-hot)
        f32x4 an0, an1;
        {
            bf16x4 a0 = *(const bf16x4*)(anb + 32 * ksp + 4 * q);
            bf16x4 a1 = *(const bf16x4*)(anb + 32 * ksp + 16 + 4 * q);
#pragma unroll
            for (int j = 0; j < 4; ++j) { an0[j] = (float)a0[j]; an1[j] = (float)a1[j]; }
        }

        __builtin_amdgcn_s_setprio(1);
#pragma unroll
        for (int rs = 0; rs < 2; ++rs) {
            f32x4 alo = an0, ahi = an1;
#pragma unroll
            for (int ks = 0; ks < 4; ++ks) {
                alo = __builtin_amdgcn_mfma_f32_16x16x32_bf16(af0[ks], xf[rs][ks], alo, 0, 0, 0);
                ahi = __builtin_amdgcn_mfma_f32_16x16x32_bf16(af1[ks], xf[rs][ks], ahi, 0, 0, 0);
            }
            bf16x8 bfrag;
#pragma unroll
            for (int j = 0; j < 4; ++j) {
                bfrag[j]     = (__bf16)fmaxf(alo[j], 0.0f);
                bfrag[4 + j] = (__bf16)fmaxf(ahi[j], 0.0f);
            }
#pragma unroll
            for (int mt2 = 0; mt2 < 4; ++mt2)
                acc2[rs][mt2] = __builtin_amdgcn_mfma_f32_16x16x32_bf16(a2f[mt2], bfrag, acc2[rs][mt2], 0, 0, 0);
        }
        __builtin_amdgcn_s_setprio(0);
    }

    // ---- layer 3: relu(h2).W3 + b3, reduce over q-groups, sigmoid ----
    const float b3v = b3[0];
#pragma unroll
    for (int rs = 0; rs < 2; ++rs) {
        float sum = 0.f;
#pragma unroll
        for (int mt2 = 0; mt2 < 4; ++mt2) {
            float4 w3v = *(const float4*)(W3 + 16 * mt2 + 4 * q);
            sum += fmaxf(acc2[rs][mt2][0], 0.f) * w3v.x
                 + fmaxf(acc2[rs][mt2][1], 0.f) * w3v.y
                 + fmaxf(acc2[rs][mt2][2], 0.f) * w3v.z
                 + fmaxf(acc2[rs][mt2][3], 0.f) * w3v.w;
        }
        sum += __shfl_xor(sum, 16, 64);
        sum += __shfl_xor(sum, 32, 64);
        if (q == 0) {
            float v = sum + b3v;
            out[row0 + 32 * w + 16 * rs + ln] = 1.0f / (1.0f + __expf(-v));
        }
    }
}

// ---------------------------------------------------------------------------
// fp32 fallback if workspace is too small
// ---------------------------------------------------------------------------
__global__ __launch_bounds__(256, 4) void edge_mlp_f32(
    const float* __restrict__ nodes, const float* __restrict__ newn,
    const float* __restrict__ W1, const float* __restrict__ b1,
    const float* __restrict__ W2, const float* __restrict__ b2,
    const float* __restrict__ W3, const float* __restrict__ b3,
    float* __restrict__ out)
{
    __shared__ float buf[32][256];
    const int t = threadIdx.x;
    const long r0 = (long)blockIdx.x * 32;
    const int b = (int)(r0 >> 12);
    const float4* src = (const float4*)(nodes + (size_t)r0 * HH);
#pragma unroll
    for (int i = 0; i < 4; ++i) {
        int idx = t + i * 256;
        *(float4*)&buf[idx >> 5][(idx & 31) * 4] = src[idx];
    }
    {
        float nv = newn[b * HH + (t & 127)];
        for (int r = (t >> 7); r < 32; r += 2) buf[r][HH + (t & 127)] = nv;
    }
    __syncthreads();
    const int c0 = t & 63, rb = (t >> 6) * 8;
    float acc[8][4];
#pragma unroll
    for (int ci = 0; ci < 4; ++ci) {
        float bv = b1[c0 + 64 * ci];
#pragma unroll
        for (int r = 0; r < 8; ++r) acc[r][ci] = bv;
    }
    for (int k = 0; k < 256; k += 4) {
        float wv[4][4];
#pragma unroll
        for (int kk = 0; kk < 4; ++kk)
#pragma unroll
            for (int ci = 0; ci < 4; ++ci) wv[kk][ci] = W1[(k + kk) * N1 + c0 + 64 * ci];
#pragma unroll
        for (int r = 0; r < 8; ++r) {
            float4 x = *(const float4*)&buf[rb + r][k];
#pragma unroll
            for (int ci = 0; ci < 4; ++ci) {
                acc[r][ci] = fmaf(x.x, wv[0][ci], acc[r][ci]);
                acc[r][ci] = fmaf(x.y, wv[1][ci], acc[r][ci]);
                acc[r][ci] = fmaf(x.z, wv[2][ci], acc[r][ci]);
                acc[r][ci] = fmaf(x.w, wv[3][ci], acc[r][ci]);
            }
        }
    }
    __syncthreads();
#pragma unroll
    for (int r = 0; r < 8; ++r)
#pragma unroll
        for (int ci = 0; ci < 4; ++ci) buf[rb + r][c0 + 64 * ci] = fmaxf(acc[r][ci], 0.0f);
    __syncthreads();
    const int c2 = t & 31, g2 = t >> 5;
    float acc2[4][2];
#pragma unroll
    for (int cj = 0; cj < 2; ++cj) {
        float bv = b2[c2 + 32 * cj];
#pragma unroll
        for (int rr = 0; rr < 4; ++rr) acc2[rr][cj] = bv;
    }
    for (int k = 0; k < 256; k += 4) {
        float w2v[4][2];
#pragma unroll
        for (int kk = 0; kk < 4; ++kk)
#pragma unroll
            for (int cj = 0; cj < 2; ++cj) w2v[kk][cj] = W2[(k + kk) * N2 + c2 + 32 * cj];
#pragma unroll
        for (int rr = 0; rr < 4; ++rr) {
            float4 x = *(const float4*)&buf[4 * g2 + rr][k];
#pragma unroll
            for (int cj = 0; cj < 2; ++cj) {
                acc2[rr][cj] = fmaf(x.x, w2v[0][cj], acc2[rr][cj]);
                acc2[rr][cj] = fmaf(x.y, w2v[1][cj], acc2[rr][cj]);
                acc2[rr][cj] = fmaf(x.z, w2v[2][cj], acc2[rr][cj]);
                acc2[rr][cj] = fmaf(x.w, w2v[3][cj], acc2[rr][cj]);
            }
        }
    }
    const float w3a = W3[c2], w3b = W3[c2 + 32], b3v = b3[0];
    float p[4];
#pragma unroll
    for (int rr = 0; rr < 4; ++rr)
        p[rr] = fmaf(fmaxf(acc2[rr][0], 0.f), w3a, fmaxf(acc2[rr][1], 0.f) * w3b);
#pragma unroll
    for (int off = 16; off >= 1; off >>= 1)
#pragma unroll
        for (int rr = 0; rr < 4; ++rr) p[rr] += __shfl_xor(p[rr], off, 64);
    if (c2 == 0)
#pragma unroll
        for (int rr = 0; rr < 4; ++rr)
            out[r0 + 4 * g2 + rr] = 1.0f / (1.0f + __expf(-(p[rr] + b3v)));
}

extern "C" void kernel_launch(void* const* d_in, const int* in_sizes, int n_in,
                              void* d_out, int out_size, void* d_ws, size_t ws_size,
                              hipStream_t stream) {
    const float* nodes = (const float*)d_in[0];
    const float* newn  = (const float*)d_in[1];
    const float* W1    = (const float*)d_in[2];
    const float* b1    = (const float*)d_in[3];
    const float* W2    = (const float*)d_in[4];
    const float* b2    = (const float*)d_in[5];
    const float* W3    = (const float*)d_in[6];
    const float* b3    = (const float*)d_in[7];
    float* out = (float*)d_out;
    const int M = BB * SS;

    if (ws_size >= 163840) {               // 64K w1f + 32K w2f + 64K an
        __bf16* w1f = (__bf16*)d_ws;                   // 32768 elems
        __bf16* w2f = (__bf16*)d_ws + 32768;           // 16384 elems
        __bf16* anp = (__bf16*)d_ws + 49152;           // 32768 elems
        hipLaunchKernelGGL(prologue, dim3(24 + BB), dim3(256), 0, stream,
                           W1, W2, b1, newn, w1f, w2f, anp);
        hipLaunchKernelGGL(edge_mlp_mfma9, dim3(M / BROWS), dim3(512), 0, stream,
                           nodes, b2, W3, b3, w1f, w2f, anp, out);
    } else {
        hipLaunchKernelGGL(edge_mlp_f32, dim3(M / 32), dim3(256), 0, stream,
                           nodes, newn, W1, b1, W2, b2, W3, b3, out);
    }
}

// Round 12
// 100.658 us; speedup vs baseline: 2.0553x; 2.0481x over previous
//
#include <hip/hip_runtime.h>
#include <hip/hip_bf16.h>
#include <cstdint>
#include <cstddef>

#define BB 128
#define SS 4096
#define HH 128
#define N1 256
#define N2 64
#define BROWS 256   // rows per block = 8 waves * 32 rows; 256 | 4096 -> one b per block

typedef __bf16 bf16x8 __attribute__((ext_vector_type(8)));
typedef __bf16 bf16x4 __attribute__((ext_vector_type(4)));
typedef float  f32x4  __attribute__((ext_vector_type(4)));

// ---------------------------------------------------------------------------
// Merged prologue (layouts verified rounds 4-10).
// Blocks 0..23: weight frags. Blocks 24..151: an partial.
// w1f (nodes half, 64 KB): frag(g 0..15, ks 0..3):
//   val[l][j] = W1[32ks + 8*(l>>4) + j][16g + (l&15)]
// w2f (32 KB): A-frags of W2^T, n-split k-slot relabel:
//   frag(mt2 0..3, ksp 0..7): val[l][j] = W2[c][16mt2 + (l&15)],
//   c = 32ksp + 16*(j>>2) + 4*(l>>4) + (j&3)
// an[b][c] = b1[c] + newn[b,:] . W1[128:256, c]
// ---------------------------------------------------------------------------
__global__ __launch_bounds__(256) void prologue(
    const float* __restrict__ W1, const float* __restrict__ W2,
    const float* __restrict__ b1, const float* __restrict__ newn,
    __bf16* __restrict__ w1f, __bf16* __restrict__ w2f, __bf16* __restrict__ an)
{
    const int blk = blockIdx.x;
    if (blk < 24) {
        int tid = blk * 256 + threadIdx.x;
        if (tid < 4096) {                        // W1 nodes half: 16 g * 4 ks * 64 lanes
            int lane = tid & 63, ks = (tid >> 6) & 3, g = tid >> 8;
            int col = 16 * g + (lane & 15);
            int kbase = 32 * ks + 8 * (lane >> 4);
            bf16x8 v;
#pragma unroll
            for (int j = 0; j < 8; ++j) v[j] = (__bf16)W1[(size_t)(kbase + j) * N1 + col];
            *(bf16x8*)(w1f + (size_t)tid * 8) = v;
        } else {                                 // W2: 4 mt2 * 8 ksp * 64 lanes
            int s = tid - 4096;
            int lane = s & 63, ksp = (s >> 6) & 7, mt2 = s >> 9;
            int q = lane >> 4, ln = lane & 15;
            bf16x8 v;
#pragma unroll
            for (int j = 0; j < 8; ++j) {
                int c = 32 * ksp + 16 * (j >> 2) + 4 * q + (j & 3);
                v[j] = (__bf16)W2[(size_t)c * N2 + 16 * mt2 + ln];
            }
            *(bf16x8*)(w2f + (size_t)s * 8) = v;
        }
    } else {
        const int b = blk - 24, c = threadIdx.x;
        float acc = b1[c];
        const float* wp = W1 + (size_t)HH * N1 + c;   // rows 128..255, col c
        const float* nv = newn + (size_t)b * HH;
#pragma unroll 8
        for (int k = 0; k < HH; ++k)
            acc = fmaf(nv[k], wp[(size_t)k * N1], acc);
        an[(size_t)b * N1 + c] = (__bf16)acc;
    }
}

// ---------------------------------------------------------------------------
// Main kernel = EXACT round-8 structure (best measured: 83.7 us) with ONE
// single-variable addition: s_setprio(1) around the MFMA/cvt region.
// 512 threads = 8 waves; wave w owns rows 32w..32w+31 (2 rowsets of 16).
// X loads issue FIRST, then w1 LDS staging, then the single barrier (its
// vmcnt(0) drain covers both bursts in one HBM round-trip -- round 9 proved
// reordering costs ~25 us). w1 (64 KB) in LDS -> 2 blocks/CU, 4 waves/SIMD.
// w2 frags (32 KB, L1/L2-hot broadcast) stream via VMEM per ksp.
// ksp loop stays unroll 1: round 10 proved unroll 2 spills catastrophically
// under the 128-VGPR launch_bounds cap (WRITE_SIZE 2MB -> 298MB).
// setprio rationale: waves de-phase after the single barrier (no per-ksp
// barrier), giving load-phase vs MFMA-phase diversity for the CU scheduler.
// ---------------------------------------------------------------------------
__global__ __launch_bounds__(512, 4) void edge_mlp_mfma10(
    const float* __restrict__ nodes,
    const float* __restrict__ b2,
    const float* __restrict__ W3, const float* __restrict__ b3,
    const __bf16* __restrict__ w1f,    // 32768 elems in ws
    const __bf16* __restrict__ w2f,    // 16384 elems in ws
    const __bf16* __restrict__ an,
    float* __restrict__ out)
{
    __shared__ __bf16 w1s[32768];      // 64 KB

    const int t = threadIdx.x;
    const int w = t >> 6, l = t & 63, q = l >> 4, ln = l & 15;
    const size_t row0 = (size_t)blockIdx.x * BROWS;
    const int b = (int)(row0 >> 12);

    // ---- X frags (global->reg, issued BEFORE staging/barrier): [rs][ks] ----
    bf16x8 xf[2][4];
#pragma unroll
    for (int rs = 0; rs < 2; ++rs) {
        const float* rp = nodes + (row0 + 32 * w + 16 * rs + ln) * HH + 8 * q;
#pragma unroll
        for (int ks = 0; ks < 4; ++ks) {
            float4 f0 = *(const float4*)(rp + 32 * ks);
            float4 f1 = *(const float4*)(rp + 32 * ks + 4);
            bf16x8 v;
            v[0] = (__bf16)f0.x; v[1] = (__bf16)f0.y; v[2] = (__bf16)f0.z; v[3] = (__bf16)f0.w;
            v[4] = (__bf16)f1.x; v[5] = (__bf16)f1.y; v[6] = (__bf16)f1.z; v[7] = (__bf16)f1.w;
            xf[rs][ks] = v;
        }
    }

    // ---- stage w1 frags: 4096 uint4 = 64 KB, coalesced flat copy ----
#pragma unroll
    for (int i = 0; i < 8; ++i) {
        int idx = i * 512 + t;
        ((uint4*)w1s)[idx] = ((const uint4*)w1f)[idx];
    }

    // ---- h2 accumulators [rs][mt2], bias-initialized ----
    f32x4 acc2[2][4];
#pragma unroll
    for (int mt2 = 0; mt2 < 4; ++mt2) {
        float4 bv = *(const float4*)(b2 + 16 * mt2 + 4 * q);
#pragma unroll
        for (int rs = 0; rs < 2; ++rs) {
            acc2[rs][mt2][0] = bv.x; acc2[rs][mt2][1] = bv.y;
            acc2[rs][mt2][2] = bv.z; acc2[rs][mt2][3] = bv.w;
        }
    }

    const __bf16* anb = an + (size_t)b * N1;

    __syncthreads();   // one drain covers staging + X loads together

    // ---- main loop over g-pairs / layer-2 k-steps ----
#pragma unroll 1
    for (int ksp = 0; ksp < 8; ++ksp) {
        bf16x8 af0[4], af1[4], a2f[4];
#pragma unroll
        for (int ks = 0; ks < 4; ++ks) {
            af0[ks] = *(const bf16x8*)(w1s + ((size_t)((2 * ksp)     * 4 + ks) * 64 + l) * 8);
            af1[ks] = *(const bf16x8*)(w1s + ((size_t)((2 * ksp + 1) * 4 + ks) * 64 + l) * 8);
        }
#pragma unroll
        for (int mt2 = 0; mt2 < 4; ++mt2)
            a2f[mt2] = *(const bf16x8*)(w2f + ((size_t)(mt2 * 8 + ksp) * 64 + l) * 8);

        // newn+bias partial for this g-pair (broadcast 8B loads, L1-hot)
        f32x4 an0, an1;
        {
            bf16x4 a0 = *(const bf16x4*)(anb + 32 * ksp + 4 * q);
            bf16x4 a1 = *(const bf16x4*)(anb + 32 * ksp + 16 + 4 * q);
#pragma unroll
            for (int j = 0; j < 4; ++j) { an0[j] = (float)a0[j]; an1[j] = (float)a1[j]; }
        }

        __builtin_amdgcn_s_setprio(1);
#pragma unroll
        for (int rs = 0; rs < 2; ++rs) {
            f32x4 alo = an0, ahi = an1;
#pragma unroll
            for (int ks = 0; ks < 4; ++ks) {
                alo = __builtin_amdgcn_mfma_f32_16x16x32_bf16(af0[ks], xf[rs][ks], alo, 0, 0, 0);
                ahi = __builtin_amdgcn_mfma_f32_16x16x32_bf16(af1[ks], xf[rs][ks], ahi, 0, 0, 0);
            }
            bf16x8 bfrag;
#pragma unroll
            for (int j = 0; j < 4; ++j) {
                bfrag[j]     = (__bf16)fmaxf(alo[j], 0.0f);
                bfrag[4 + j] = (__bf16)fmaxf(ahi[j], 0.0f);
            }
#pragma unroll
            for (int mt2 = 0; mt2 < 4; ++mt2)
                acc2[rs][mt2] = __builtin_amdgcn_mfma_f32_16x16x32_bf16(a2f[mt2], bfrag, acc2[rs][mt2], 0, 0, 0);
        }
        __builtin_amdgcn_s_setprio(0);
    }

    // ---- layer 3: relu(h2).W3 + b3, reduce over q-groups, sigmoid ----
    const float b3v = b3[0];
#pragma unroll
    for (int rs = 0; rs < 2; ++rs) {
        float sum = 0.f;
#pragma unroll
        for (int mt2 = 0; mt2 < 4; ++mt2) {
            float4 w3v = *(const float4*)(W3 + 16 * mt2 + 4 * q);
            sum += fmaxf(acc2[rs][mt2][0], 0.f) * w3v.x
                 + fmaxf(acc2[rs][mt2][1], 0.f) * w3v.y
                 + fmaxf(acc2[rs][mt2][2], 0.f) * w3v.z
                 + fmaxf(acc2[rs][mt2][3], 0.f) * w3v.w;
        }
        sum += __shfl_xor(sum, 16, 64);
        sum += __shfl_xor(sum, 32, 64);
        if (q == 0) {
            float v = sum + b3v;
            out[row0 + 32 * w + 16 * rs + ln] = 1.0f / (1.0f + __expf(-v));
        }
    }
}

// ---------------------------------------------------------------------------
// fp32 fallback if workspace is too small
// ---------------------------------------------------------------------------
__global__ __launch_bounds__(256, 4) void edge_mlp_f32(
    const float* __restrict__ nodes, const float* __restrict__ newn,
    const float* __restrict__ W1, const float* __restrict__ b1,
    const float* __restrict__ W2, const float* __restrict__ b2,
    const float* __restrict__ W3, const float* __restrict__ b3,
    float* __restrict__ out)
{
    __shared__ float buf[32][256];
    const int t = threadIdx.x;
    const long r0 = (long)blockIdx.x * 32;
    const int b = (int)(r0 >> 12);
    const float4* src = (const float4*)(nodes + (size_t)r0 * HH);
#pragma unroll
    for (int i = 0; i < 4; ++i) {
        int idx = t + i * 256;
        *(float4*)&buf[idx >> 5][(idx & 31) * 4] = src[idx];
    }
    {
        float nv = newn[b * HH + (t & 127)];
        for (int r = (t >> 7); r < 32; r += 2) buf[r][HH + (t & 127)] = nv;
    }
    __syncthreads();
    const int c0 = t & 63, rb = (t >> 6) * 8;
    float acc[8][4];
#pragma unroll
    for (int ci = 0; ci < 4; ++ci) {
        float bv = b1[c0 + 64 * ci];
#pragma unroll
        for (int r = 0; r < 8; ++r) acc[r][ci] = bv;
    }
    for (int k = 0; k < 256; k += 4) {
        float wv[4][4];
#pragma unroll
        for (int kk = 0; kk < 4; ++kk)
#pragma unroll
            for (int ci = 0; ci < 4; ++ci) wv[kk][ci] = W1[(k + kk) * N1 + c0 + 64 * ci];
#pragma unroll
        for (int r = 0; r < 8; ++r) {
            float4 x = *(const float4*)&buf[rb + r][k];
#pragma unroll
            for (int ci = 0; ci < 4; ++ci) {
                acc[r][ci] = fmaf(x.x, wv[0][ci], acc[r][ci]);
                acc[r][ci] = fmaf(x.y, wv[1][ci], acc[r][ci]);
                acc[r][ci] = fmaf(x.z, wv[2][ci], acc[r][ci]);
                acc[r][ci] = fmaf(x.w, wv[3][ci], acc[r][ci]);
            }
        }
    }
    __syncthreads();
#pragma unroll
    for (int r = 0; r < 8; ++r)
#pragma unroll
        for (int ci = 0; ci < 4; ++ci) buf[rb + r][c0 + 64 * ci] = fmaxf(acc[r][ci], 0.0f);
    __syncthreads();
    const int c2 = t & 31, g2 = t >> 5;
    float acc2[4][2];
#pragma unroll
    for (int cj = 0; cj < 2; ++cj) {
        float bv = b2[c2 + 32 * cj];
#pragma unroll
        for (int rr = 0; rr < 4; ++rr) acc2[rr][cj] = bv;
    }
    for (int k = 0; k < 256; k += 4) {
        float w2v[4][2];
#pragma unroll
        for (int kk = 0; kk < 4; ++kk)
#pragma unroll
            for (int cj = 0; cj < 2; ++cj) w2v[kk][cj] = W2[(k + kk) * N2 + c2 + 32 * cj];
#pragma unroll
        for (int rr = 0; rr < 4; ++rr) {
            float4 x = *(const float4*)&buf[4 * g2 + rr][k];
#pragma unroll
            for (int cj = 0; cj < 2; ++cj) {
                acc2[rr][cj] = fmaf(x.x, w2v[0][cj], acc2[rr][cj]);
                acc2[rr][cj] = fmaf(x.y, w2v[1][cj], acc2[rr][cj]);
                acc2[rr][cj] = fmaf(x.z, w2v[2][cj], acc2[rr][cj]);
                acc2[rr][cj] = fmaf(x.w, w2v[3][cj], acc2[rr][cj]);
            }
        }
    }
    const float w3a = W3[c2], w3b = W3[c2 + 32], b3v = b3[0];
    float p[4];
#pragma unroll
    for (int rr = 0; rr < 4; ++rr)
        p[rr] = fmaf(fmaxf(acc2[rr][0], 0.f), w3a, fmaxf(acc2[rr][1], 0.f) * w3b);
#pragma unroll
    for (int off = 16; off >= 1; off >>= 1)
#pragma unroll
        for (int rr = 0; rr < 4; ++rr) p[rr] += __shfl_xor(p[rr], off, 64);
    if (c2 == 0)
#pragma unroll
        for (int rr = 0; rr < 4; ++rr)
            out[r0 + 4 * g2 + rr] = 1.0f / (1.0f + __expf(-(p[rr] + b3v)));
}

extern "C" void kernel_launch(void* const* d_in, const int* in_sizes, int n_in,
                              void* d_out, int out_size, void* d_ws, size_t ws_size,
                              hipStream_t stream) {
    const float* nodes = (const float*)d_in[0];
    const float* newn  = (const float*)d_in[1];
    const float* W1    = (const float*)d_in[2];
    const float* b1    = (const float*)d_in[3];
    const float* W2    = (const float*)d_in[4];
    const float* b2    = (const float*)d_in[5];
    const float* W3    = (const float*)d_in[6];
    const float* b3    = (const float*)d_in[7];
    float* out = (float*)d_out;
    const int M = BB * SS;

    if (ws_size >= 163840) {               // 64K w1f + 32K w2f + 64K an
        __bf16* w1f = (__bf16*)d_ws;                   // 32768 elems
        __bf16* w2f = (__bf16*)d_ws + 32768;           // 16384 elems
        __bf16* anp = (__bf16*)d_ws + 49152;           // 32768 elems
        hipLaunchKernelGGL(prologue, dim3(24 + BB), dim3(256), 0, stream,
                           W1, W2, b1, newn, w1f, w2f, anp);
        hipLaunchKernelGGL(edge_mlp_mfma10, dim3(M / BROWS), dim3(512), 0, stream,
                           nodes, b2, W3, b3, w1f, w2f, anp, out);
    } else {
        hipLaunchKernelGGL(edge_mlp_f32, dim3(M / 32), dim3(256), 0, stream,
                           nodes, newn, W1, b1, W2, b2, W3, b3, out);
    }
}

// Round 13
// 83.325 us; speedup vs baseline: 2.4828x; 1.2080x over previous
//
#include <hip/hip_runtime.h>
#include <hip/hip_bf16.h>
#include <cstdint>
#include <cstddef>

#define BB 128
#define SS 4096
#define HH 128
#define N1 256
#define N2 64
#define BROWS 256   // rows per block = 8 waves * 32 rows; 256 | 4096 -> one b per block

typedef __bf16 bf16x8 __attribute__((ext_vector_type(8)));
typedef __bf16 bf16x4 __attribute__((ext_vector_type(4)));
typedef float  f32x4  __attribute__((ext_vector_type(4)));

// ---------------------------------------------------------------------------
// Merged prologue (layouts verified rounds 4-12).
// Blocks 0..23: weight frags. Blocks 24..151: an partial.
// w1f (nodes half, 64 KB): frag(g 0..15, ks 0..3):
//   val[l][j] = W1[32ks + 8*(l>>4) + j][16g + (l&15)]
// w2f (32 KB): A-frags of W2^T, n-split k-slot relabel:
//   frag(mt2 0..3, ksp 0..7): val[l][j] = W2[c][16mt2 + (l&15)],
//   c = 32ksp + 16*(j>>2) + 4*(l>>4) + (j&3)
// an[b][c] = b1[c] + newn[b,:] . W1[128:256, c]
// ---------------------------------------------------------------------------
__global__ __launch_bounds__(256) void prologue(
    const float* __restrict__ W1, const float* __restrict__ W2,
    const float* __restrict__ b1, const float* __restrict__ newn,
    __bf16* __restrict__ w1f, __bf16* __restrict__ w2f, __bf16* __restrict__ an)
{
    const int blk = blockIdx.x;
    if (blk < 24) {
        int tid = blk * 256 + threadIdx.x;
        if (tid < 4096) {                        // W1 nodes half: 16 g * 4 ks * 64 lanes
            int lane = tid & 63, ks = (tid >> 6) & 3, g = tid >> 8;
            int col = 16 * g + (lane & 15);
            int kbase = 32 * ks + 8 * (lane >> 4);
            bf16x8 v;
#pragma unroll
            for (int j = 0; j < 8; ++j) v[j] = (__bf16)W1[(size_t)(kbase + j) * N1 + col];
            *(bf16x8*)(w1f + (size_t)tid * 8) = v;
        } else {                                 // W2: 4 mt2 * 8 ksp * 64 lanes
            int s = tid - 4096;
            int lane = s & 63, ksp = (s >> 6) & 7, mt2 = s >> 9;
            int q = lane >> 4, ln = lane & 15;
            bf16x8 v;
#pragma unroll
            for (int j = 0; j < 8; ++j) {
                int c = 32 * ksp + 16 * (j >> 2) + 4 * q + (j & 3);
                v[j] = (__bf16)W2[(size_t)c * N2 + 16 * mt2 + ln];
            }
            *(bf16x8*)(w2f + (size_t)s * 8) = v;
        }
    } else {
        const int b = blk - 24, c = threadIdx.x;
        float acc = b1[c];
        const float* wp = W1 + (size_t)HH * N1 + c;   // rows 128..255, col c
        const float* nv = newn + (size_t)b * HH;
#pragma unroll 8
        for (int k = 0; k < HH; ++k)
            acc = fmaf(nv[k], wp[(size_t)k * N1], acc);
        an[(size_t)b * N1 + c] = (__bf16)acc;
    }
}

// ---------------------------------------------------------------------------
// Main kernel = EXACT round-8 configuration (best measured: 83.7 us).
// 512 threads = 8 waves; wave w owns rows 32w..32w+31 (2 rowsets of 16).
// X loads issue FIRST, then w1 LDS staging, then the single barrier: the
// barrier's vmcnt(0) drain covers both bursts in one HBM round-trip.
// w1 (64 KB) in LDS -> 2 blocks/CU resident, 4 waves/SIMD (VGPR<=128);
// cross-block wave TLP provides the load/compute overlap.
// w2 frags (32 KB, L1/L2-hot broadcast) stream via VMEM per ksp.
// Measured-and-rejected deltas on this structure (keep it as-is):
//  - loads AFTER barrier (r9): +25 us (serializes the two bursts)
//  - ksp unroll 2 under (512,4) (r10): VGPR spill, WRITE 2MB->298MB, +120 us
//  - s_setprio around MFMA cluster (r12): +17 us (starves sibling waves'
//    load issue; this kernel is latency-bound, not MFMA-issue-bound)
// ---------------------------------------------------------------------------
__global__ __launch_bounds__(512, 4) void edge_mlp_mfma11(
    const float* __restrict__ nodes,
    const float* __restrict__ b2,
    const float* __restrict__ W3, const float* __restrict__ b3,
    const __bf16* __restrict__ w1f,    // 32768 elems in ws
    const __bf16* __restrict__ w2f,    // 16384 elems in ws
    const __bf16* __restrict__ an,
    float* __restrict__ out)
{
    __shared__ __bf16 w1s[32768];      // 64 KB

    const int t = threadIdx.x;
    const int w = t >> 6, l = t & 63, q = l >> 4, ln = l & 15;
    const size_t row0 = (size_t)blockIdx.x * BROWS;
    const int b = (int)(row0 >> 12);

    // ---- X frags (global->reg, issued BEFORE staging/barrier): [rs][ks] ----
    bf16x8 xf[2][4];
#pragma unroll
    for (int rs = 0; rs < 2; ++rs) {
        const float* rp = nodes + (row0 + 32 * w + 16 * rs + ln) * HH + 8 * q;
#pragma unroll
        for (int ks = 0; ks < 4; ++ks) {
            float4 f0 = *(const float4*)(rp + 32 * ks);
            float4 f1 = *(const float4*)(rp + 32 * ks + 4);
            bf16x8 v;
            v[0] = (__bf16)f0.x; v[1] = (__bf16)f0.y; v[2] = (__bf16)f0.z; v[3] = (__bf16)f0.w;
            v[4] = (__bf16)f1.x; v[5] = (__bf16)f1.y; v[6] = (__bf16)f1.z; v[7] = (__bf16)f1.w;
            xf[rs][ks] = v;
        }
    }

    // ---- stage w1 frags: 4096 uint4 = 64 KB, coalesced flat copy ----
#pragma unroll
    for (int i = 0; i < 8; ++i) {
        int idx = i * 512 + t;
        ((uint4*)w1s)[idx] = ((const uint4*)w1f)[idx];
    }

    // ---- h2 accumulators [rs][mt2], bias-initialized ----
    f32x4 acc2[2][4];
#pragma unroll
    for (int mt2 = 0; mt2 < 4; ++mt2) {
        float4 bv = *(const float4*)(b2 + 16 * mt2 + 4 * q);
#pragma unroll
        for (int rs = 0; rs < 2; ++rs) {
            acc2[rs][mt2][0] = bv.x; acc2[rs][mt2][1] = bv.y;
            acc2[rs][mt2][2] = bv.z; acc2[rs][mt2][3] = bv.w;
        }
    }

    const __bf16* anb = an + (size_t)b * N1;

    __syncthreads();   // one drain covers staging + X loads together

    // ---- main loop over g-pairs / layer-2 k-steps ----
#pragma unroll 1
    for (int ksp = 0; ksp < 8; ++ksp) {
        bf16x8 af0[4], af1[4], a2f[4];
#pragma unroll
        for (int ks = 0; ks < 4; ++ks) {
            af0[ks] = *(const bf16x8*)(w1s + ((size_t)((2 * ksp)     * 4 + ks) * 64 + l) * 8);
            af1[ks] = *(const bf16x8*)(w1s + ((size_t)((2 * ksp + 1) * 4 + ks) * 64 + l) * 8);
        }
#pragma unroll
        for (int mt2 = 0; mt2 < 4; ++mt2)
            a2f[mt2] = *(const bf16x8*)(w2f + ((size_t)(mt2 * 8 + ksp) * 64 + l) * 8);

        // newn+bias partial for this g-pair (broadcast 8B loads, L1-hot)
        f32x4 an0, an1;
        {
            bf16x4 a0 = *(const bf16x4*)(anb + 32 * ksp + 4 * q);
            bf16x4 a1 = *(const bf16x4*)(anb + 32 * ksp + 16 + 4 * q);
#pragma unroll
            for (int j = 0; j < 4; ++j) { an0[j] = (float)a0[j]; an1[j] = (float)a1[j]; }
        }

#pragma unroll
        for (int rs = 0; rs < 2; ++rs) {
            f32x4 alo = an0, ahi = an1;
#pragma unroll
            for (int ks = 0; ks < 4; ++ks) {
                alo = __builtin_amdgcn_mfma_f32_16x16x32_bf16(af0[ks], xf[rs][ks], alo, 0, 0, 0);
                ahi = __builtin_amdgcn_mfma_f32_16x16x32_bf16(af1[ks], xf[rs][ks], ahi, 0, 0, 0);
            }
            bf16x8 bfrag;
#pragma unroll
            for (int j = 0; j < 4; ++j) {
                bfrag[j]     = (__bf16)fmaxf(alo[j], 0.0f);
                bfrag[4 + j] = (__bf16)fmaxf(ahi[j], 0.0f);
            }
#pragma unroll
            for (int mt2 = 0; mt2 < 4; ++mt2)
                acc2[rs][mt2] = __builtin_amdgcn_mfma_f32_16x16x32_bf16(a2f[mt2], bfrag, acc2[rs][mt2], 0, 0, 0);
        }
    }

    // ---- layer 3: relu(h2).W3 + b3, reduce over q-groups, sigmoid ----
    const float b3v = b3[0];
#pragma unroll
    for (int rs = 0; rs < 2; ++rs) {
        float sum = 0.f;
#pragma unroll
        for (int mt2 = 0; mt2 < 4; ++mt2) {
            float4 w3v = *(const float4*)(W3 + 16 * mt2 + 4 * q);
            sum += fmaxf(acc2[rs][mt2][0], 0.f) * w3v.x
                 + fmaxf(acc2[rs][mt2][1], 0.f) * w3v.y
                 + fmaxf(acc2[rs][mt2][2], 0.f) * w3v.z
                 + fmaxf(acc2[rs][mt2][3], 0.f) * w3v.w;
        }
        sum += __shfl_xor(sum, 16, 64);
        sum += __shfl_xor(sum, 32, 64);
        if (q == 0) {
            float v = sum + b3v;
            out[row0 + 32 * w + 16 * rs + ln] = 1.0f / (1.0f + __expf(-v));
        }
    }
}

// ---------------------------------------------------------------------------
// fp32 fallback if workspace is too small
// ---------------------------------------------------------------------------
__global__ __launch_bounds__(256, 4) void edge_mlp_f32(
    const float* __restrict__ nodes, const float* __restrict__ newn,
    const float* __restrict__ W1, const float* __restrict__ b1,
    const float* __restrict__ W2, const float* __restrict__ b2,
    const float* __restrict__ W3, const float* __restrict__ b3,
    float* __restrict__ out)
{
    __shared__ float buf[32][256];
    const int t = threadIdx.x;
    const long r0 = (long)blockIdx.x * 32;
    const int b = (int)(r0 >> 12);
    const float4* src = (const float4*)(nodes + (size_t)r0 * HH);
#pragma unroll
    for (int i = 0; i < 4; ++i) {
        int idx = t + i * 256;
        *(float4*)&buf[idx >> 5][(idx & 31) * 4] = src[idx];
    }
    {
        float nv = newn[b * HH + (t & 127)];
        for (int r = (t >> 7); r < 32; r += 2) buf[r][HH + (t & 127)] = nv;
    }
    __syncthreads();
    const int c0 = t & 63, rb = (t >> 6) * 8;
    float acc[8][4];
#pragma unroll
    for (int ci = 0; ci < 4; ++ci) {
        float bv = b1[c0 + 64 * ci];
#pragma unroll
        for (int r = 0; r < 8; ++r) acc[r][ci] = bv;
    }
    for (int k = 0; k < 256; k += 4) {
        float wv[4][4];
#pragma unroll
        for (int kk = 0; kk < 4; ++kk)
#pragma unroll
            for (int ci = 0; ci < 4; ++ci) wv[kk][ci] = W1[(k + kk) * N1 + c0 + 64 * ci];
#pragma unroll
        for (int r = 0; r < 8; ++r) {
            float4 x = *(const float4*)&buf[rb + r][k];
#pragma unroll
            for (int ci = 0; ci < 4; ++ci) {
                acc[r][ci] = fmaf(x.x, wv[0][ci], acc[r][ci]);
                acc[r][ci] = fmaf(x.y, wv[1][ci], acc[r][ci]);
                acc[r][ci] = fmaf(x.z, wv[2][ci], acc[r][ci]);
                acc[r][ci] = fmaf(x.w, wv[3][ci], acc[r][ci]);
            }
        }
    }
    __syncthreads();
#pragma unroll
    for (int r = 0; r < 8; ++r)
#pragma unroll
        for (int ci = 0; ci < 4; ++ci) buf[rb + r][c0 + 64 * ci] = fmaxf(acc[r][ci], 0.0f);
    __syncthreads();
    const int c2 = t & 31, g2 = t >> 5;
    float acc2[4][2];
#pragma unroll
    for (int cj = 0; cj < 2; ++cj) {
        float bv = b2[c2 + 32 * cj];
#pragma unroll
        for (int rr = 0; rr < 4; ++rr) acc2[rr][cj] = bv;
    }
    for (int k = 0; k < 256; k += 4) {
        float w2v[4][2];
#pragma unroll
        for (int kk = 0; kk < 4; ++kk)
#pragma unroll
            for (int cj = 0; cj < 2; ++cj) w2v[kk][cj] = W2[(k + kk) * N2 + c2 + 32 * cj];
#pragma unroll
        for (int rr = 0; rr < 4; ++rr) {
            float4 x = *(const float4*)&buf[4 * g2 + rr][k];
#pragma unroll
            for (int cj = 0; cj < 2; ++cj) {
                acc2[rr][cj] = fmaf(x.x, w2v[0][cj], acc2[rr][cj]);
                acc2[rr][cj] = fmaf(x.y, w2v[1][cj], acc2[rr][cj]);
                acc2[rr][cj] = fmaf(x.z, w2v[2][cj], acc2[rr][cj]);
                acc2[rr][cj] = fmaf(x.w, w2v[3][cj], acc2[rr][cj]);
            }
        }
    }
    const float w3a = W3[c2], w3b = W3[c2 + 32], b3v = b3[0];
    float p[4];
#pragma unroll
    for (int rr = 0; rr < 4; ++rr)
        p[rr] = fmaf(fmaxf(acc2[rr][0], 0.f), w3a, fmaxf(acc2[rr][1], 0.f) * w3b);
#pragma unroll
    for (int off = 16; off >= 1; off >>= 1)
#pragma unroll
        for (int rr = 0; rr < 4; ++rr) p[rr] += __shfl_xor(p[rr], off, 64);
    if (c2 == 0)
#pragma unroll
        for (int rr = 0; rr < 4; ++rr)
            out[r0 + 4 * g2 + rr] = 1.0f / (1.0f + __expf(-(p[rr] + b3v)));
}

extern "C" void kernel_launch(void* const* d_in, const int* in_sizes, int n_in,
                              void* d_out, int out_size, void* d_ws, size_t ws_size,
                              hipStream_t stream) {
    const float* nodes = (const float*)d_in[0];
    const float* newn  = (const float*)d_in[1];
    const float* W1    = (const float*)d_in[2];
    const float* b1    = (const float*)d_in[3];
    const float* W2    = (const float*)d_in[4];
    const float* b2    = (const float*)d_in[5];
    const float* W3    = (const float*)d_in[6];
    const float* b3    = (const float*)d_in[7];
    float* out = (float*)d_out;
    const int M = BB * SS;

    if (ws_size >= 163840) {               // 64K w1f + 32K w2f + 64K an
        __bf16* w1f = (__bf16*)d_ws;                   // 32768 elems
        __bf16* w2f = (__bf16*)d_ws + 32768;           // 16384 elems
        __bf16* anp = (__bf16*)d_ws + 49152;           // 32768 elems
        hipLaunchKernelGGL(prologue, dim3(24 + BB), dim3(256), 0, stream,
                           W1, W2, b1, newn, w1f, w2f, anp);
        hipLaunchKernelGGL(edge_mlp_mfma11, dim3(M / BROWS), dim3(512), 0, stream,
                           nodes, b2, W3, b3, w1f, w2f, anp, out);
    } else {
        hipLaunchKernelGGL(edge_mlp_f32, dim3(M / 32), dim3(256), 0, stream,
                           nodes, newn, W1, b1, W2, b2, W3, b3, out);
    }
}